// Round 2
// baseline (229.447 us; speedup 1.0000x reference)
//
#include <hip/hip_runtime.h>
#include <hip/hip_bf16.h>

typedef short v8s __attribute__((ext_vector_type(8)));
typedef float v4f __attribute__((ext_vector_type(4)));

#define MFMA16(a, b, c) __builtin_amdgcn_mfma_f32_16x16x32_bf16((a), (b), (c), 0, 0, 0)

constexpr int Bsz   = 128;
constexpr int Lq    = 32;
constexpr int Ld    = 512;
constexpr int H     = 768;
constexpr int D     = 128;
constexpr int QROWS = Bsz * Lq;          // 4096
constexpr int DROWS = Bsz * Ld;          // 65536
constexpr int MTOT  = QROWS + 2 * DROWS; // 135168
static_assert(MTOT % 128 == 0, "rows divisible by 128");

// f32 -> bf16 bits, round-to-nearest-even (inputs are finite; no NaN path needed)
static __device__ __forceinline__ unsigned short f2b(float f) {
    unsigned int u = __builtin_bit_cast(unsigned int, f);
    unsigned int r = u + 0x7FFFu + ((u >> 16) & 1u);
    return (unsigned short)(r >> 16);
}

// ---------------------------------------------------------------------------
// Kernel 1: Wt[d][h] = bf16(W[h][d])   (so B-fragments are contiguous 16B)
// ---------------------------------------------------------------------------
__global__ void prep_w_kernel(const float* __restrict__ W,
                              unsigned short* __restrict__ Wt) {
    int idx = blockIdx.x * 256 + threadIdx.x;
    if (idx < H * D) {
        int d = idx / H, h = idx % H;
        Wt[idx] = f2b(W[h * D + d]);
    }
}

// ---------------------------------------------------------------------------
// Kernel 2: project 32 rows per wave, 4 waves per block (128 rows/block),
//           bias, L2-norm, mask, write normalized bf16 embeddings.
//           No LDS; register double-buffer.
// ---------------------------------------------------------------------------
struct Frag {
    float4 fa[4]; // A raw f32: rows (m=0,m=1) x 8 floats
    v8s    wb[8]; // B bf16 fragments for 8 N-tiles
};

__global__ __launch_bounds__(256, 4) void proj_norm_kernel(
    const float* __restrict__ qh, const float* __restrict__ pdh,
    const float* __restrict__ ndh, const float* __restrict__ bias,
    const int* __restrict__ pdm, const int* __restrict__ ndm,
    const unsigned short* __restrict__ Wt, unsigned short* __restrict__ emb)
{
    const int lane = threadIdx.x & 63;
    const int wave = threadIdx.x >> 6;
    const int l15  = lane & 15, lg = lane >> 4;
    const long row0 = ((long)blockIdx.x * 4 + wave) * 32;

    const float* src; const int* mask; long srow;
    if (row0 < QROWS)              { src = qh;  srow = row0;                 mask = nullptr; }
    else if (row0 < QROWS + DROWS) { src = pdh; srow = row0 - QROWS;         mask = pdm; }
    else                           { src = ndh; srow = row0 - QROWS - DROWS; mask = ndm; }

    float bv[8];
#pragma unroll
    for (int n = 0; n < 8; ++n) bv[n] = bias[n * 16 + l15];

    const float* a0p = src + (srow + l15) * (long)H + lg * 8;
    const float* a1p = a0p + (long)16 * H;
    const unsigned short* wp = Wt + (size_t)l15 * H + lg * 8;

    v4f acc[2][8];
#pragma unroll
    for (int m = 0; m < 2; ++m)
#pragma unroll
        for (int n = 0; n < 8; ++n) acc[m][n] = (v4f){0.f, 0.f, 0.f, 0.f};

    auto load_frag = [&](int kk, Frag& f) {
        const float* p0 = a0p + kk * 32;
        const float* p1 = a1p + kk * 32;
        f.fa[0] = *(const float4*)(p0);
        f.fa[1] = *(const float4*)(p0 + 4);
        f.fa[2] = *(const float4*)(p1);
        f.fa[3] = *(const float4*)(p1 + 4);
#pragma unroll
        for (int n = 0; n < 8; ++n)
            f.wb[n] = *(const v8s*)(wp + (size_t)n * 16 * H + kk * 32);
    };

    auto do_mfma = [&](Frag& f) {
        v8s a0, a1;
        a0[0] = (short)f2b(f.fa[0].x); a0[1] = (short)f2b(f.fa[0].y);
        a0[2] = (short)f2b(f.fa[0].z); a0[3] = (short)f2b(f.fa[0].w);
        a0[4] = (short)f2b(f.fa[1].x); a0[5] = (short)f2b(f.fa[1].y);
        a0[6] = (short)f2b(f.fa[1].z); a0[7] = (short)f2b(f.fa[1].w);
        a1[0] = (short)f2b(f.fa[2].x); a1[1] = (short)f2b(f.fa[2].y);
        a1[2] = (short)f2b(f.fa[2].z); a1[3] = (short)f2b(f.fa[2].w);
        a1[4] = (short)f2b(f.fa[3].x); a1[5] = (short)f2b(f.fa[3].y);
        a1[6] = (short)f2b(f.fa[3].z); a1[7] = (short)f2b(f.fa[3].w);
#pragma unroll
        for (int n = 0; n < 8; ++n) {
            acc[0][n] = MFMA16(a0, f.wb[n], acc[0][n]);
            acc[1][n] = MFMA16(a1, f.wb[n], acc[1][n]);
        }
    };

    Frag fX, fY;
    load_frag(0, fX);
#pragma unroll 1
    for (int kk = 0; kk < 22; kk += 2) {
        load_frag(kk + 1, fY);
        do_mfma(fX);
        load_frag(kk + 2, fX);
        do_mfma(fY);
    }
    load_frag(23, fY);
    do_mfma(fX);
    do_mfma(fY);

    // epilogue: bias, sum-of-squares across the 16 lanes holding each row,
    // rsqrt scale (0 if masked), store bf16
#pragma unroll
    for (int m = 0; m < 2; ++m) {
        float ss[4] = {0.f, 0.f, 0.f, 0.f};
#pragma unroll
        for (int n = 0; n < 8; ++n) {
            v4f v = acc[m][n];
            v[0] += bv[n]; v[1] += bv[n]; v[2] += bv[n]; v[3] += bv[n];
            acc[m][n] = v;
            ss[0] += v[0] * v[0]; ss[1] += v[1] * v[1];
            ss[2] += v[2] * v[2]; ss[3] += v[3] * v[3];
        }
#pragma unroll
        for (int off = 1; off < 16; off <<= 1) {
            ss[0] += __shfl_xor(ss[0], off);
            ss[1] += __shfl_xor(ss[1], off);
            ss[2] += __shfl_xor(ss[2], off);
            ss[3] += __shfl_xor(ss[3], off);
        }
        float sc[4];
#pragma unroll
        for (int r = 0; r < 4; ++r) {
            float s = 1.0f / fmaxf(sqrtf(ss[r]), 1e-12f);
            if (mask) s *= (float)mask[srow + m * 16 + lg * 4 + r];
            sc[r] = s;
        }
        unsigned short* op = emb + (size_t)(row0 + m * 16 + lg * 4) * D + l15;
#pragma unroll
        for (int n = 0; n < 8; ++n)
#pragma unroll
            for (int r = 0; r < 4; ++r)
                op[(size_t)r * D + n * 16] = f2b(acc[m][n][r] * sc[r]);
    }
}

// ---------------------------------------------------------------------------
// Kernel 3: MaxSim. One block per (batch, side); 4 waves x 128 doc tokens.
// scores = Q[32x128] . Dtok[*x128]^T via MFMA, max over tokens, sum over q.
// ---------------------------------------------------------------------------
__global__ __launch_bounds__(256) void maxsim_kernel(
    const unsigned short* __restrict__ emb, float* __restrict__ out)
{
    const int blk  = blockIdx.x;       // 0..255
    const int b    = blk >> 1, side = blk & 1;
    const int wave = threadIdx.x >> 6, lane = threadIdx.x & 63;
    const int l15  = lane & 15, lg = lane >> 4;

    const unsigned short* Q  = emb + (size_t)(b * Lq) * D;
    const unsigned short* Dm = emb + (size_t)(QROWS + side * DROWS + b * Ld) * D;

    v4f acc[2][8];
#pragma unroll
    for (int m = 0; m < 2; ++m)
#pragma unroll
        for (int n = 0; n < 8; ++n) acc[m][n] = (v4f){0.f, 0.f, 0.f, 0.f};

    const int tok0 = wave * 128;
#pragma unroll
    for (int kk = 0; kk < 4; ++kk) {
        const int k0 = kk * 32 + lg * 8;
        v8s qa0 = *(const v8s*)(Q + (size_t)(l15) * D + k0);
        v8s qa1 = *(const v8s*)(Q + (size_t)(16 + l15) * D + k0);
#pragma unroll
        for (int n = 0; n < 8; ++n) {
            v8s db = *(const v8s*)(Dm + (size_t)(tok0 + n * 16 + l15) * D + k0);
            acc[0][n] = MFMA16(qa0, db, acc[0][n]);
            acc[1][n] = MFMA16(qa1, db, acc[1][n]);
        }
    }

    // per-q max over this wave's 128 tokens
    float mx[2][4];
#pragma unroll
    for (int m = 0; m < 2; ++m)
#pragma unroll
        for (int r = 0; r < 4; ++r) {
            float v = acc[m][0][r];
#pragma unroll
            for (int n = 1; n < 8; ++n) v = fmaxf(v, acc[m][n][r]);
            mx[m][r] = v;
        }
#pragma unroll
    for (int off = 1; off < 16; off <<= 1) {
#pragma unroll
        for (int m = 0; m < 2; ++m)
#pragma unroll
            for (int r = 0; r < 4; ++r)
                mx[m][r] = fmaxf(mx[m][r], __shfl_xor(mx[m][r], off));
    }

    __shared__ float red[4][32];
    if (l15 == 0) {
#pragma unroll
        for (int m = 0; m < 2; ++m)
#pragma unroll
            for (int r = 0; r < 4; ++r)
                red[wave][m * 16 + lg * 4 + r] = mx[m][r];
    }
    __syncthreads();

    if (threadIdx.x < 32) {
        int q = threadIdx.x;
        float v = fmaxf(fmaxf(red[0][q], red[1][q]), fmaxf(red[2][q], red[3][q]));
#pragma unroll
        for (int off = 1; off < 32; off <<= 1) v += __shfl_xor(v, off);
        if (q == 0) out[blk] = v;
    }
}

// ---------------------------------------------------------------------------
extern "C" void kernel_launch(void* const* d_in, const int* in_sizes, int n_in,
                              void* d_out, int out_size, void* d_ws, size_t ws_size,
                              hipStream_t stream)
{
    const float* qh   = (const float*)d_in[0];
    const float* pdh  = (const float*)d_in[1];
    const float* ndh  = (const float*)d_in[2];
    const float* W    = (const float*)d_in[3];
    const float* bias = (const float*)d_in[4];
    const int*   pdm  = (const int*)d_in[5];
    const int*   ndm  = (const int*)d_in[6];
    float* out = (float*)d_out;

    // workspace layout: Wt bf16 [D][H] (192KB), then emb bf16 [MTOT][D] (~34.6MB)
    unsigned short* Wt  = (unsigned short*)d_ws;
    unsigned short* emb = Wt + (size_t)H * D;

    prep_w_kernel<<<(H * D + 255) / 256, 256, 0, stream>>>(W, Wt);
    proj_norm_kernel<<<MTOT / 128, 256, 0, stream>>>(qh, pdh, ndh, bias, pdm, ndm, Wt, emb);
    maxsim_kernel<<<Bsz * 2, 256, 0, stream>>>(emb, out);
}

// Round 3
// 188.547 us; speedup vs baseline: 1.2169x; 1.2169x over previous
//
#include <hip/hip_runtime.h>
#include <hip/hip_bf16.h>

typedef short v8s __attribute__((ext_vector_type(8)));
typedef float v4f __attribute__((ext_vector_type(4)));

#define MFMA16(a, b, c) __builtin_amdgcn_mfma_f32_16x16x32_bf16((a), (b), (c), 0, 0, 0)

typedef __attribute__((address_space(1))) const void g_void;
typedef __attribute__((address_space(3))) void lds_void;
#define GLOAD_LDS16(g, l) \
    __builtin_amdgcn_global_load_lds((g_void*)(g), (lds_void*)(l), 16, 0, 0)

constexpr int Bsz   = 128;
constexpr int Lq    = 32;
constexpr int Ld    = 512;
constexpr int H     = 768;
constexpr int D     = 128;
constexpr int QROWS = Bsz * Lq;          // 4096
constexpr int DROWS = Bsz * Ld;          // 65536
constexpr int MTOT  = QROWS + 2 * DROWS; // 135168
constexpr int BM    = 128;               // rows per block (4 waves x 32)
constexpr int BK    = 32;                // K per tile
constexpr int NKT   = H / BK;            // 24 K-tiles
static_assert(QROWS % BM == 0 && DROWS % BM == 0, "block never spans sources");

// f32 -> bf16 bits, round-to-nearest-even
static __device__ __forceinline__ unsigned short f2b(float f) {
    unsigned int u = __builtin_bit_cast(unsigned int, f);
    unsigned int r = u + 0x7FFFu + ((u >> 16) & 1u);
    return (unsigned short)(r >> 16);
}

// ---------------------------------------------------------------------------
// Kernel 1: Wt[d][h] = bf16(W[h][d])
// ---------------------------------------------------------------------------
__global__ void prep_w_kernel(const float* __restrict__ W,
                              unsigned short* __restrict__ Wt) {
    int idx = blockIdx.x * 256 + threadIdx.x;
    if (idx < H * D) {
        int d = idx / H, h = idx % H;
        Wt[idx] = f2b(W[h * D + d]);
    }
}

// ---------------------------------------------------------------------------
// Kernel 2: projection. 2-phase LDS pipeline:
//   A-tile [128 rows][32 k] f32 staged via global_load_lds (dbuf, 32 KB),
//   chunk-XOR swizzled (slot = chunk ^ (row&7), 16B granule), pre-swizzled
//   global source (rule 21). B (Wt bf16) direct from L2 per K-step.
//   Each wave computes 32 rows x 128 d. Bias + L2-norm + mask epilogue.
// ---------------------------------------------------------------------------
__global__ __launch_bounds__(256, 2) void proj_norm_kernel(
    const float* __restrict__ qh, const float* __restrict__ pdh,
    const float* __restrict__ ndh, const float* __restrict__ bias,
    const int* __restrict__ pdm, const int* __restrict__ ndm,
    const unsigned short* __restrict__ Wt, unsigned short* __restrict__ emb)
{
    __shared__ float Abuf[2][BM * BK];   // 2 x 16 KB

    const int tid  = threadIdx.x;
    const int lane = tid & 63, wave = tid >> 6;
    const int l15  = lane & 15, lg = lane >> 4;
    const long row0 = (long)blockIdx.x * BM;

    const float* src; const int* mask; long srow;
    if (row0 < QROWS)              { src = qh;  srow = row0;                 mask = nullptr; }
    else if (row0 < QROWS + DROWS) { src = pdh; srow = row0 - QROWS;         mask = pdm; }
    else                           { src = ndh; srow = row0 - QROWS - DROWS; mask = ndm; }

    // ---- staging constants (per thread) ----
    // thread covers local row rloc = tid>>3 of each 32-row slice, LDS slot tid&7;
    // source chunk pre-swizzled so LDS[r][slot] holds global chunk slot^(r&7).
    const int rloc = tid >> 3;                    // 0..31
    const int cs   = (tid & 7) ^ (rloc & 7);      // swizzled source chunk
    const float* gsrc = src + (srow + rloc) * (long)H + cs * 4;

    float bv[8];
#pragma unroll
    for (int n = 0; n < 8; ++n) bv[n] = bias[n * 16 + l15];

    const unsigned short* wp = Wt + (size_t)l15 * H + lg * 8;

    v4f acc[2][8];
#pragma unroll
    for (int m = 0; m < 2; ++m)
#pragma unroll
        for (int n = 0; n < 8; ++n) acc[m][n] = (v4f){0.f, 0.f, 0.f, 0.f};

    auto stage = [&](int nb, int kt) {
        const float* gp = gsrc + (size_t)kt * BK;
#pragma unroll
        for (int it = 0; it < 4; ++it) {
            float* lp = &Abuf[nb][(it * 32 + wave * 8) * BK];
            GLOAD_LDS16(gp + (size_t)it * 32 * H, lp);
        }
    };

    // prologue: stage tile 0
    stage(0, 0);
    __syncthreads();

    // swizzled read slots (constant per lane)
    const int slot0 = (2 * lg)     ^ (l15 & 7);
    const int slot1 = (2 * lg + 1) ^ (l15 & 7);

#pragma unroll 1
    for (int kt = 0; kt < NKT; ++kt) {
        const int cur = kt & 1;
        const int k0  = kt * BK;

        // B for this K-step (L2-resident; latency hides under ds_read+convert)
        v8s wb[8];
#pragma unroll
        for (int n = 0; n < 8; ++n)
            wb[n] = *(const v8s*)(wp + (size_t)n * 16 * H + k0);

        // prefetch next A-tile into other buffer
        if (kt < NKT - 1) stage(cur ^ 1, kt + 1);

        // A fragments from LDS (swizzled), convert f32->bf16
        v8s am[2];
#pragma unroll
        for (int m = 0; m < 2; ++m) {
            const int r = wave * 32 + m * 16 + l15;
            const float* rp = &Abuf[cur][r * BK];
            float4 f0 = *(const float4*)(rp + slot0 * 4);
            float4 f1 = *(const float4*)(rp + slot1 * 4);
            v8s a;
            a[0] = (short)f2b(f0.x); a[1] = (short)f2b(f0.y);
            a[2] = (short)f2b(f0.z); a[3] = (short)f2b(f0.w);
            a[4] = (short)f2b(f1.x); a[5] = (short)f2b(f1.y);
            a[6] = (short)f2b(f1.z); a[7] = (short)f2b(f1.w);
            am[m] = a;
        }

#pragma unroll
        for (int n = 0; n < 8; ++n) {
            acc[0][n] = MFMA16(am[0], wb[n], acc[0][n]);
            acc[1][n] = MFMA16(am[1], wb[n], acc[1][n]);
        }

        __syncthreads();   // drains stage(kt+1) loads (vmcnt 0) + LDS reads
    }

    // ---- epilogue: bias, L2-norm across the 16 lanes holding each row ----
#pragma unroll
    for (int m = 0; m < 2; ++m) {
        float ss[4] = {0.f, 0.f, 0.f, 0.f};
#pragma unroll
        for (int n = 0; n < 8; ++n) {
            v4f v = acc[m][n];
            v[0] += bv[n]; v[1] += bv[n]; v[2] += bv[n]; v[3] += bv[n];
            acc[m][n] = v;
            ss[0] += v[0] * v[0]; ss[1] += v[1] * v[1];
            ss[2] += v[2] * v[2]; ss[3] += v[3] * v[3];
        }
#pragma unroll
        for (int off = 1; off < 16; off <<= 1) {
            ss[0] += __shfl_xor(ss[0], off);
            ss[1] += __shfl_xor(ss[1], off);
            ss[2] += __shfl_xor(ss[2], off);
            ss[3] += __shfl_xor(ss[3], off);
        }
        float sc[4];
#pragma unroll
        for (int r = 0; r < 4; ++r) {
            float s = 1.0f / fmaxf(sqrtf(ss[r]), 1e-12f);
            if (mask) s *= (float)mask[srow + wave * 32 + m * 16 + lg * 4 + r];
            sc[r] = s;
        }
        unsigned short* op = emb + (size_t)(row0 + wave * 32 + m * 16 + lg * 4) * D + l15;
#pragma unroll
        for (int n = 0; n < 8; ++n)
#pragma unroll
            for (int r = 0; r < 4; ++r)
                op[(size_t)r * D + n * 16] = f2b(acc[m][n][r] * sc[r]);
    }
}

// ---------------------------------------------------------------------------
// Kernel 3: MaxSim. One block per (batch, side); 4 waves x 128 doc tokens.
// ---------------------------------------------------------------------------
__global__ __launch_bounds__(256) void maxsim_kernel(
    const unsigned short* __restrict__ emb, float* __restrict__ out)
{
    const int blk  = blockIdx.x;       // 0..255
    const int b    = blk >> 1, side = blk & 1;
    const int wave = threadIdx.x >> 6, lane = threadIdx.x & 63;
    const int l15  = lane & 15, lg = lane >> 4;

    const unsigned short* Q  = emb + (size_t)(b * Lq) * D;
    const unsigned short* Dm = emb + (size_t)(QROWS + side * DROWS + b * Ld) * D;

    v4f acc[2][8];
#pragma unroll
    for (int m = 0; m < 2; ++m)
#pragma unroll
        for (int n = 0; n < 8; ++n) acc[m][n] = (v4f){0.f, 0.f, 0.f, 0.f};

    const int tok0 = wave * 128;
#pragma unroll
    for (int kk = 0; kk < 4; ++kk) {
        const int k0 = kk * 32 + lg * 8;
        v8s qa0 = *(const v8s*)(Q + (size_t)(l15) * D + k0);
        v8s qa1 = *(const v8s*)(Q + (size_t)(16 + l15) * D + k0);
#pragma unroll
        for (int n = 0; n < 8; ++n) {
            v8s db = *(const v8s*)(Dm + (size_t)(tok0 + n * 16 + l15) * D + k0);
            acc[0][n] = MFMA16(qa0, db, acc[0][n]);
            acc[1][n] = MFMA16(qa1, db, acc[1][n]);
        }
    }

    float mx[2][4];
#pragma unroll
    for (int m = 0; m < 2; ++m)
#pragma unroll
        for (int r = 0; r < 4; ++r) {
            float v = acc[m][0][r];
#pragma unroll
            for (int n = 1; n < 8; ++n) v = fmaxf(v, acc[m][n][r]);
            mx[m][r] = v;
        }
#pragma unroll
    for (int off = 1; off < 16; off <<= 1) {
#pragma unroll
        for (int m = 0; m < 2; ++m)
#pragma unroll
            for (int r = 0; r < 4; ++r)
                mx[m][r] = fmaxf(mx[m][r], __shfl_xor(mx[m][r], off));
    }

    __shared__ float red[4][32];
    if (l15 == 0) {
#pragma unroll
        for (int m = 0; m < 2; ++m)
#pragma unroll
            for (int r = 0; r < 4; ++r)
                red[wave][m * 16 + lg * 4 + r] = mx[m][r];
    }
    __syncthreads();

    if (threadIdx.x < 32) {
        int q = threadIdx.x;
        float v = fmaxf(fmaxf(red[0][q], red[1][q]), fmaxf(red[2][q], red[3][q]));
#pragma unroll
        for (int off = 1; off < 32; off <<= 1) v += __shfl_xor(v, off);
        if (q == 0) out[blk] = v;
    }
}

// ---------------------------------------------------------------------------
extern "C" void kernel_launch(void* const* d_in, const int* in_sizes, int n_in,
                              void* d_out, int out_size, void* d_ws, size_t ws_size,
                              hipStream_t stream)
{
    const float* qh   = (const float*)d_in[0];
    const float* pdh  = (const float*)d_in[1];
    const float* ndh  = (const float*)d_in[2];
    const float* W    = (const float*)d_in[3];
    const float* bias = (const float*)d_in[4];
    const int*   pdm  = (const int*)d_in[5];
    const int*   ndm  = (const int*)d_in[6];
    float* out = (float*)d_out;

    unsigned short* Wt  = (unsigned short*)d_ws;          // [D][H] bf16, 192 KB
    unsigned short* emb = Wt + (size_t)H * D;             // [MTOT][D] bf16

    prep_w_kernel<<<(H * D + 255) / 256, 256, 0, stream>>>(W, Wt);
    proj_norm_kernel<<<MTOT / BM, 256, 0, stream>>>(qh, pdh, ndh, bias, pdm, ndm, Wt, emb);
    maxsim_kernel<<<Bsz * 2, 256, 0, stream>>>(emb, out);
}

// Round 4
// 184.286 us; speedup vs baseline: 1.2451x; 1.0231x over previous
//
#include <hip/hip_runtime.h>
#include <hip/hip_bf16.h>

typedef short v8s __attribute__((ext_vector_type(8)));
typedef float v4f __attribute__((ext_vector_type(4)));

#define MFMA16(a, b, c) __builtin_amdgcn_mfma_f32_16x16x32_bf16((a), (b), (c), 0, 0, 0)

typedef __attribute__((address_space(1))) const void g_void;
typedef __attribute__((address_space(3))) void lds_void;
#define GLOAD_LDS16(g, l) \
    __builtin_amdgcn_global_load_lds((g_void*)(g), (lds_void*)(l), 16, 0, 0)

constexpr int Bsz   = 128;
constexpr int Lq    = 32;
constexpr int Ld    = 512;
constexpr int H     = 768;
constexpr int D     = 128;
constexpr int QROWS = Bsz * Lq;          // 4096
constexpr int DROWS = Bsz * Ld;          // 65536
constexpr int MTOT  = QROWS + 2 * DROWS; // 135168
constexpr int BM    = 32;                // rows per block
constexpr int CH    = 256;               // f32 columns per staged chunk (1 KB/row)
constexpr int NCH   = H / CH;            // 3 chunks
constexpr int NKI   = CH / 32;           // 8 K-iters per chunk
static_assert(QROWS % BM == 0 && DROWS % BM == 0, "block never spans sources");

// f32 -> bf16 bits, round-to-nearest-even
static __device__ __forceinline__ unsigned short f2b(float f) {
    unsigned int u = __builtin_bit_cast(unsigned int, f);
    unsigned int r = u + 0x7FFFu + ((u >> 16) & 1u);
    return (unsigned short)(r >> 16);
}

// ---------------------------------------------------------------------------
// Kernel 1: Wt[d][h] = bf16(W[h][d])
// ---------------------------------------------------------------------------
__global__ void prep_w_kernel(const float* __restrict__ W,
                              unsigned short* __restrict__ Wt) {
    int idx = blockIdx.x * 256 + threadIdx.x;
    if (idx < H * D) {
        int d = idx / H, h = idx % H;
        Wt[idx] = f2b(W[h * D + d]);
    }
}

// ---------------------------------------------------------------------------
// Kernel 2: projection with CONTIGUOUS HBM staging.
//   Block = 32 rows. Chunk = [32][256] f32 (32 KB), double-buffered (64 KB).
//   Each global_load_lds instruction reads one full 1 KB row segment
//   contiguously (lane l -> 16B chunk l^(r&7): XOR pre-swizzle on the source,
//   matching XOR on the ds_read side — rule 21 both-sides).
//   Waves split D: wave w owns cols [32w, 32w+32). Row L2-norm reduced
//   across waves via LDS.
// ---------------------------------------------------------------------------
__global__ __launch_bounds__(256, 2) void proj_norm_kernel(
    const float* __restrict__ qh, const float* __restrict__ pdh,
    const float* __restrict__ ndh, const float* __restrict__ bias,
    const int* __restrict__ pdm, const int* __restrict__ ndm,
    const unsigned short* __restrict__ Wt, unsigned short* __restrict__ emb)
{
    __shared__ float Abuf[2][BM * CH];   // 2 x 32 KB
    __shared__ float ssred[4][BM];       // cross-wave norm partials

    const int tid  = threadIdx.x;
    const int lane = tid & 63, wave = tid >> 6;
    const int l15  = lane & 15, lg = lane >> 4;
    const long row0 = (long)blockIdx.x * BM;

    const float* src; const int* mask; long srow;
    if (row0 < QROWS)              { src = qh;  srow = row0;                 mask = nullptr; }
    else if (row0 < QROWS + DROWS) { src = pdh; srow = row0 - QROWS;         mask = pdm; }
    else                           { src = ndh; srow = row0 - QROWS - DROWS; mask = ndm; }

    // bias for this wave's 32-col slice (n-tiles 2w, 2w+1)
    float bv[2];
#pragma unroll
    for (int n = 0; n < 2; ++n) bv[n] = bias[wave * 32 + n * 16 + l15];

    // stage one [32][256] chunk: instruction i covers row r = i*4+wave fully;
    // lane l reads 16B chunk (l ^ (r&7)) of that row -> contiguous 1 KB burst.
    auto stage = [&](int nb, int ch) {
        const int cb = ch * CH;
#pragma unroll
        for (int i = 0; i < 8; ++i) {
            const int r  = i * 4 + wave;
            const int jl = lane ^ (r & 7);
            const float* gp = src + (srow + r) * (long)H + cb + jl * 4;
            float* lp = &Abuf[nb][i * 1024 + wave * 256];
            GLOAD_LDS16(gp, lp);
        }
    };

    v4f acc[2][2];
#pragma unroll
    for (int m = 0; m < 2; ++m)
#pragma unroll
        for (int n = 0; n < 2; ++n) acc[m][n] = (v4f){0.f, 0.f, 0.f, 0.f};

    const unsigned short* wp = Wt + (size_t)(wave * 32 + l15) * H + lg * 8;

    stage(0, 0);
    __syncthreads();

#pragma unroll 1
    for (int ch = 0; ch < NCH; ++ch) {
        const int cur = ch & 1;
        if (ch + 1 < NCH) stage(cur ^ 1, ch + 1);

        const int k0 = ch * CH;
#pragma unroll
        for (int kk = 0; kk < NKI; ++kk) {
            // B fragments (Wt, L2-resident)
            v8s wb[2];
#pragma unroll
            for (int n = 0; n < 2; ++n)
                wb[n] = *(const v8s*)(wp + (size_t)n * 16 * H + k0 + kk * 32);

            // A fragments from LDS (XOR-swizzled), convert f32->bf16
            v8s am[2];
#pragma unroll
            for (int m = 0; m < 2; ++m) {
                const int r  = m * 16 + l15;
                const float* rp = &Abuf[cur][r * CH];
                const int j0 = (kk * 8 + 2 * lg)     ^ (r & 7);
                const int j1 = (kk * 8 + 2 * lg + 1) ^ (r & 7);
                float4 f0 = *(const float4*)(rp + j0 * 4);
                float4 f1 = *(const float4*)(rp + j1 * 4);
                v8s a;
                a[0] = (short)f2b(f0.x); a[1] = (short)f2b(f0.y);
                a[2] = (short)f2b(f0.z); a[3] = (short)f2b(f0.w);
                a[4] = (short)f2b(f1.x); a[5] = (short)f2b(f1.y);
                a[6] = (short)f2b(f1.z); a[7] = (short)f2b(f1.w);
                am[m] = a;
            }
#pragma unroll
            for (int m = 0; m < 2; ++m)
#pragma unroll
                for (int n = 0; n < 2; ++n)
                    acc[m][n] = MFMA16(am[m], wb[n], acc[m][n]);
        }
        __syncthreads();  // stage loads arrived; all waves done reading cur
    }

    // ---- epilogue: bias, cross-wave L2-norm, mask, store bf16 ----
    float ss[2][4];
#pragma unroll
    for (int m = 0; m < 2; ++m)
#pragma unroll
        for (int r = 0; r < 4; ++r) {
            float s = 0.f;
#pragma unroll
            for (int n = 0; n < 2; ++n) {
                float v = acc[m][n][r] + bv[n];
                acc[m][n][r] = v;
                s += v * v;
            }
            ss[m][r] = s;
        }
#pragma unroll
    for (int off = 1; off < 16; off <<= 1)
#pragma unroll
        for (int m = 0; m < 2; ++m)
#pragma unroll
            for (int r = 0; r < 4; ++r)
                ss[m][r] += __shfl_xor(ss[m][r], off);

    if (l15 == 0) {
#pragma unroll
        for (int m = 0; m < 2; ++m)
#pragma unroll
            for (int r = 0; r < 4; ++r)
                ssred[wave][m * 16 + lg * 4 + r] = ss[m][r];
    }
    __syncthreads();

    float sc[2][4];
#pragma unroll
    for (int m = 0; m < 2; ++m)
#pragma unroll
        for (int r = 0; r < 4; ++r) {
            const int row = m * 16 + lg * 4 + r;
            float t = ssred[0][row] + ssred[1][row] + ssred[2][row] + ssred[3][row];
            float s = 1.0f / fmaxf(sqrtf(t), 1e-12f);
            if (mask) s *= (float)mask[srow + row];
            sc[m][r] = s;
        }

#pragma unroll
    for (int m = 0; m < 2; ++m)
#pragma unroll
        for (int n = 0; n < 2; ++n)
#pragma unroll
            for (int r = 0; r < 4; ++r)
                emb[(size_t)(row0 + m * 16 + lg * 4 + r) * D + wave * 32 + n * 16 + l15]
                    = f2b(acc[m][n][r] * sc[m][r]);
}

// ---------------------------------------------------------------------------
// Kernel 3: MaxSim. One block per (batch, side); 4 waves x 128 doc tokens.
// ---------------------------------------------------------------------------
__global__ __launch_bounds__(256) void maxsim_kernel(
    const unsigned short* __restrict__ emb, float* __restrict__ out)
{
    const int blk  = blockIdx.x;       // 0..255
    const int b    = blk >> 1, side = blk & 1;
    const int wave = threadIdx.x >> 6, lane = threadIdx.x & 63;
    const int l15  = lane & 15, lg = lane >> 4;

    const unsigned short* Q  = emb + (size_t)(b * Lq) * D;
    const unsigned short* Dm = emb + (size_t)(QROWS + side * DROWS + b * Ld) * D;

    v4f acc[2][8];
#pragma unroll
    for (int m = 0; m < 2; ++m)
#pragma unroll
        for (int n = 0; n < 8; ++n) acc[m][n] = (v4f){0.f, 0.f, 0.f, 0.f};

    const int tok0 = wave * 128;
#pragma unroll
    for (int kk = 0; kk < 4; ++kk) {
        const int k0 = kk * 32 + lg * 8;
        v8s qa0 = *(const v8s*)(Q + (size_t)(l15) * D + k0);
        v8s qa1 = *(const v8s*)(Q + (size_t)(16 + l15) * D + k0);
#pragma unroll
        for (int n = 0; n < 8; ++n) {
            v8s db = *(const v8s*)(Dm + (size_t)(tok0 + n * 16 + l15) * D + k0);
            acc[0][n] = MFMA16(qa0, db, acc[0][n]);
            acc[1][n] = MFMA16(qa1, db, acc[1][n]);
        }
    }

    float mx[2][4];
#pragma unroll
    for (int m = 0; m < 2; ++m)
#pragma unroll
        for (int r = 0; r < 4; ++r) {
            float v = acc[m][0][r];
#pragma unroll
            for (int n = 1; n < 8; ++n) v = fmaxf(v, acc[m][n][r]);
            mx[m][r] = v;
        }
#pragma unroll
    for (int off = 1; off < 16; off <<= 1) {
#pragma unroll
        for (int m = 0; m < 2; ++m)
#pragma unroll
            for (int r = 0; r < 4; ++r)
                mx[m][r] = fmaxf(mx[m][r], __shfl_xor(mx[m][r], off));
    }

    __shared__ float red[4][32];
    if (l15 == 0) {
#pragma unroll
        for (int m = 0; m < 2; ++m)
#pragma unroll
            for (int r = 0; r < 4; ++r)
                red[wave][m * 16 + lg * 4 + r] = mx[m][r];
    }
    __syncthreads();

    if (threadIdx.x < 32) {
        int q = threadIdx.x;
        float v = fmaxf(fmaxf(red[0][q], red[1][q]), fmaxf(red[2][q], red[3][q]));
#pragma unroll
        for (int off = 1; off < 32; off <<= 1) v += __shfl_xor(v, off);
        if (q == 0) out[blk] = v;
    }
}

// ---------------------------------------------------------------------------
extern "C" void kernel_launch(void* const* d_in, const int* in_sizes, int n_in,
                              void* d_out, int out_size, void* d_ws, size_t ws_size,
                              hipStream_t stream)
{
    const float* qh   = (const float*)d_in[0];
    const float* pdh  = (const float*)d_in[1];
    const float* ndh  = (const float*)d_in[2];
    const float* W    = (const float*)d_in[3];
    const float* bias = (const float*)d_in[4];
    const int*   pdm  = (const int*)d_in[5];
    const int*   ndm  = (const int*)d_in[6];
    float* out = (float*)d_out;

    unsigned short* Wt  = (unsigned short*)d_ws;          // [D][H] bf16, 192 KB
    unsigned short* emb = Wt + (size_t)H * D;             // [MTOT][D] bf16

    prep_w_kernel<<<(H * D + 255) / 256, 256, 0, stream>>>(W, Wt);
    proj_norm_kernel<<<MTOT / BM, 256, 0, stream>>>(qh, pdh, ndh, bias, pdm, ndm, Wt, emb);
    maxsim_kernel<<<Bsz * 2, 256, 0, stream>>>(emb, out);
}

// Round 5
// 179.454 us; speedup vs baseline: 1.2786x; 1.0269x over previous
//
#include <hip/hip_runtime.h>
#include <hip/hip_bf16.h>

typedef short v8s __attribute__((ext_vector_type(8)));
typedef float v4f __attribute__((ext_vector_type(4)));

#define MFMA16(a, b, c) __builtin_amdgcn_mfma_f32_16x16x32_bf16((a), (b), (c), 0, 0, 0)

typedef __attribute__((address_space(1))) const void g_void;
typedef __attribute__((address_space(3))) void lds_void;
#define GLOAD_LDS16(g, l) \
    __builtin_amdgcn_global_load_lds((g_void*)(g), (lds_void*)(l), 16, 0, 0)

constexpr int Bsz   = 128;
constexpr int Lq    = 32;
constexpr int Ld    = 512;
constexpr int H     = 768;
constexpr int D     = 128;
constexpr int QROWS = Bsz * Lq;          // 4096
constexpr int DROWS = Bsz * Ld;          // 65536
constexpr int MTOT  = QROWS + 2 * DROWS; // 135168
constexpr int BM    = 128;               // rows per block
constexpr int BK    = 32;                // K per tile (16 KB f32)
constexpr int NKT   = H / BK;            // 24 K-tiles
constexpr int NBUF  = 4;                 // LDS ring depth
static_assert(QROWS % BM == 0 && DROWS % BM == 0, "block never spans sources");

// f32 -> bf16 bits, round-to-nearest-even
static __device__ __forceinline__ unsigned short f2b(float f) {
    unsigned int u = __builtin_bit_cast(unsigned int, f);
    unsigned int r = u + 0x7FFFu + ((u >> 16) & 1u);
    return (unsigned short)(r >> 16);
}

// ---------------------------------------------------------------------------
// Kernel 1: Wt[d][h] = bf16(W[h][d])
// ---------------------------------------------------------------------------
__global__ void prep_w_kernel(const float* __restrict__ W,
                              unsigned short* __restrict__ Wt) {
    int idx = blockIdx.x * 256 + threadIdx.x;
    if (idx < H * D) {
        int d = idx / H, h = idx % H;
        Wt[idx] = f2b(W[h * D + d]);
    }
}

// ---------------------------------------------------------------------------
// Kernel 2: projection with counted-vmcnt staging ring (T3+T4).
//   512 threads = 8 waves: 2 m-groups (64 rows) x 4 n-groups (32 cols).
//   A-tile [128][32] f32 = 16 KB; 4-deep LDS ring; per-iter:
//     s_waitcnt vmcnt(2) -> s_barrier -> compute buf[kt] -> loadwb(kt+1)
//     -> stage(kt+2).  Stage loads NEVER drain to 0 in the main loop.
//   LDS mapping: instr i covers rows 8i..8i+7; lane l -> row 8i+(l&7),
//   chunk (l>>3)^(l&7).  ds_read bank = f(row) -> conflict-free (2-way max).
// ---------------------------------------------------------------------------
__global__ __launch_bounds__(512, 4) void proj_norm_kernel(
    const float* __restrict__ qh, const float* __restrict__ pdh,
    const float* __restrict__ ndh, const float* __restrict__ bias,
    const int* __restrict__ pdm, const int* __restrict__ ndm,
    const unsigned short* __restrict__ Wt, unsigned short* __restrict__ emb)
{
    __shared__ float Abuf[NBUF][BM * BK];   // 4 x 16 KB
    __shared__ float ssred[4][BM];          // cross-wave norm partials (2 KB)

    const int tid  = threadIdx.x;
    const int lane = tid & 63, wave = tid >> 6;      // wave 0..7
    const int l15  = lane & 15, lg = lane >> 4;
    const int mg   = wave >> 2;                      // 0..1 (row half)
    const int ng   = wave & 3;                       // 0..3 (col quarter)
    const long row0 = (long)blockIdx.x * BM;

    const float* src; const int* mask; long srow;
    if (row0 < QROWS)              { src = qh;  srow = row0;                 mask = nullptr; }
    else if (row0 < QROWS + DROWS) { src = pdh; srow = row0 - QROWS;         mask = pdm; }
    else                           { src = ndh; srow = row0 - QROWS - DROWS; mask = ndm; }

    // ---- staging addresses: wave stages instrs {2w, 2w+1} (rows 16w..16w+15)
    const int rA = lane & 7;                  // row within 8-row group
    const int cA = (lane >> 3) ^ (lane & 7);  // swizzled 16B chunk
    const float* gs0 = src + (srow + 16 * wave     + rA) * (long)H + cA * 4;
    const float* gs1 = src + (srow + 16 * wave + 8 + rA) * (long)H + cA * 4;

    auto stage = [&](int bi, int kt) {
        GLOAD_LDS16(gs0 + kt * BK, &Abuf[bi][(2 * wave)     * 256]);
        GLOAD_LDS16(gs1 + kt * BK, &Abuf[bi][(2 * wave + 1) * 256]);
    };

    // ---- Wt fragments for this wave's 2 n-tiles, prefetched 1 tile ahead
    const unsigned short* wp = Wt + (size_t)(ng * 32 + l15) * H + lg * 8;
    v8s wbc0, wbc1, wbn0, wbn1;
    auto loadwb = [&](int kt, v8s& w0, v8s& w1) {
        w0 = *(const v8s*)(wp + (size_t)kt * BK);
        w1 = *(const v8s*)(wp + (size_t)16 * H + (size_t)kt * BK);
    };

    const float bv0 = bias[ng * 32 + l15];
    const float bv1 = bias[ng * 32 + 16 + l15];

    v4f acc[4][2];
#pragma unroll
    for (int mt = 0; mt < 4; ++mt)
#pragma unroll
        for (int nt = 0; nt < 2; ++nt) acc[mt][nt] = (v4f){0.f, 0.f, 0.f, 0.f};

    // prologue: FIFO = S0(2), W0(2), S1(2)
    stage(0, 0);
    loadwb(0, wbc0, wbc1);
    stage(1, 1);

    for (int kt = 0; kt < NKT; ++kt) {
        // completes S(kt) and W(kt); leaves S(kt+1) [, S(kt+2)] in flight
        asm volatile("s_waitcnt vmcnt(2)" ::: "memory");
        __builtin_amdgcn_sched_barrier(0);
        __builtin_amdgcn_s_barrier();

        const float* bufk = &Abuf[kt & 3][0];
#pragma unroll
        for (int mt = 0; mt < 4; ++mt) {
            const int r  = mg * 64 + mt * 16 + l15;
            const int r7 = r & 7;
            const int a0 = (r >> 3) * 256 + ((((2 * lg)     ^ r7) * 8) + r7) * 4;
            const int a1 = (r >> 3) * 256 + ((((2 * lg + 1) ^ r7) * 8) + r7) * 4;
            float4 f0 = *(const float4*)(bufk + a0);
            float4 f1 = *(const float4*)(bufk + a1);
            v8s a;
            a[0] = (short)f2b(f0.x); a[1] = (short)f2b(f0.y);
            a[2] = (short)f2b(f0.z); a[3] = (short)f2b(f0.w);
            a[4] = (short)f2b(f1.x); a[5] = (short)f2b(f1.y);
            a[6] = (short)f2b(f1.z); a[7] = (short)f2b(f1.w);
            acc[mt][0] = MFMA16(a, wbc0, acc[mt][0]);
            acc[mt][1] = MFMA16(a, wbc1, acc[mt][1]);
        }

        if (kt + 1 < NKT) loadwb(kt + 1, wbn0, wbn1);  // W before S: FIFO order
        if (kt + 2 < NKT) stage((kt + 2) & 3, kt + 2);
        wbc0 = wbn0; wbc1 = wbn1;
    }

    // ---- epilogue: bias, cross-wave L2-norm, mask, store bf16 ----
    float ss[4][4];
#pragma unroll
    for (int mt = 0; mt < 4; ++mt)
#pragma unroll
        for (int q = 0; q < 4; ++q) {
            float v0 = acc[mt][0][q] + bv0;
            float v1 = acc[mt][1][q] + bv1;
            acc[mt][0][q] = v0; acc[mt][1][q] = v1;
            ss[mt][q] = v0 * v0 + v1 * v1;
        }
#pragma unroll
    for (int off = 1; off < 16; off <<= 1)
#pragma unroll
        for (int mt = 0; mt < 4; ++mt)
#pragma unroll
            for (int q = 0; q < 4; ++q)
                ss[mt][q] += __shfl_xor(ss[mt][q], off);

    if (l15 == 0) {
#pragma unroll
        for (int mt = 0; mt < 4; ++mt)
#pragma unroll
            for (int q = 0; q < 4; ++q)
                ssred[ng][mg * 64 + mt * 16 + lg * 4 + q] = ss[mt][q];
    }
    __syncthreads();

#pragma unroll
    for (int mt = 0; mt < 4; ++mt)
#pragma unroll
        for (int q = 0; q < 4; ++q) {
            const int row = mg * 64 + mt * 16 + lg * 4 + q;
            float t = ssred[0][row] + ssred[1][row] + ssred[2][row] + ssred[3][row];
            float s = 1.0f / fmaxf(sqrtf(t), 1e-12f);
            if (mask) s *= (float)mask[srow + row];
            unsigned short* op = emb + (size_t)(row0 + row) * D + ng * 32 + l15;
            op[0]  = f2b(acc[mt][0][q] * s);
            op[16] = f2b(acc[mt][1][q] * s);
        }
}

// ---------------------------------------------------------------------------
// Kernel 3: MaxSim. One block per (batch, side); 4 waves x 128 doc tokens.
// ---------------------------------------------------------------------------
__global__ __launch_bounds__(256) void maxsim_kernel(
    const unsigned short* __restrict__ emb, float* __restrict__ out)
{
    const int blk  = blockIdx.x;       // 0..255
    const int b    = blk >> 1, side = blk & 1;
    const int wave = threadIdx.x >> 6, lane = threadIdx.x & 63;
    const int l15  = lane & 15, lg = lane >> 4;

    const unsigned short* Q  = emb + (size_t)(b * Lq) * D;
    const unsigned short* Dm = emb + (size_t)(QROWS + side * DROWS + b * Ld) * D;

    v4f acc[2][8];
#pragma unroll
    for (int m = 0; m < 2; ++m)
#pragma unroll
        for (int n = 0; n < 8; ++n) acc[m][n] = (v4f){0.f, 0.f, 0.f, 0.f};

    const int tok0 = wave * 128;
#pragma unroll
    for (int kk = 0; kk < 4; ++kk) {
        const int k0 = kk * 32 + lg * 8;
        v8s qa0 = *(const v8s*)(Q + (size_t)(l15) * D + k0);
        v8s qa1 = *(const v8s*)(Q + (size_t)(16 + l15) * D + k0);
#pragma unroll
        for (int n = 0; n < 8; ++n) {
            v8s db = *(const v8s*)(Dm + (size_t)(tok0 + n * 16 + l15) * D + k0);
            acc[0][n] = MFMA16(qa0, db, acc[0][n]);
            acc[1][n] = MFMA16(qa1, db, acc[1][n]);
        }
    }

    float mx[2][4];
#pragma unroll
    for (int m = 0; m < 2; ++m)
#pragma unroll
        for (int r = 0; r < 4; ++r) {
            float v = acc[m][0][r];
#pragma unroll
            for (int n = 1; n < 8; ++n) v = fmaxf(v, acc[m][n][r]);
            mx[m][r] = v;
        }
#pragma unroll
    for (int off = 1; off < 16; off <<= 1) {
#pragma unroll
        for (int m = 0; m < 2; ++m)
#pragma unroll
            for (int r = 0; r < 4; ++r)
                mx[m][r] = fmaxf(mx[m][r], __shfl_xor(mx[m][r], off));
    }

    __shared__ float red[4][32];
    if (l15 == 0) {
#pragma unroll
        for (int m = 0; m < 2; ++m)
#pragma unroll
            for (int r = 0; r < 4; ++r)
                red[wave][m * 16 + lg * 4 + r] = mx[m][r];
    }
    __syncthreads();

    if (threadIdx.x < 32) {
        int q = threadIdx.x;
        float v = fmaxf(fmaxf(red[0][q], red[1][q]), fmaxf(red[2][q], red[3][q]));
#pragma unroll
        for (int off = 1; off < 32; off <<= 1) v += __shfl_xor(v, off);
        if (q == 0) out[blk] = v;
    }
}

// ---------------------------------------------------------------------------
extern "C" void kernel_launch(void* const* d_in, const int* in_sizes, int n_in,
                              void* d_out, int out_size, void* d_ws, size_t ws_size,
                              hipStream_t stream)
{
    const float* qh   = (const float*)d_in[0];
    const float* pdh  = (const float*)d_in[1];
    const float* ndh  = (const float*)d_in[2];
    const float* W    = (const float*)d_in[3];
    const float* bias = (const float*)d_in[4];
    const int*   pdm  = (const int*)d_in[5];
    const int*   ndm  = (const int*)d_in[6];
    float* out = (float*)d_out;

    unsigned short* Wt  = (unsigned short*)d_ws;          // [D][H] bf16, 192 KB
    unsigned short* emb = Wt + (size_t)H * D;             // [MTOT][D] bf16

    prep_w_kernel<<<(H * D + 255) / 256, 256, 0, stream>>>(W, Wt);
    proj_norm_kernel<<<MTOT / BM, 512, 0, stream>>>(qh, pdh, ndh, bias, pdm, ndm, Wt, emb);
    maxsim_kernel<<<Bsz * 2, 256, 0, stream>>>(emb, out);
}

// Round 6
// 164.404 us; speedup vs baseline: 1.3956x; 1.0915x over previous
//
#include <hip/hip_runtime.h>
#include <hip/hip_bf16.h>

typedef short v8s __attribute__((ext_vector_type(8)));
typedef float v4f __attribute__((ext_vector_type(4)));

#define MFMA16(a, b, c) __builtin_amdgcn_mfma_f32_16x16x32_bf16((a), (b), (c), 0, 0, 0)

typedef __attribute__((address_space(1))) const void g_void;
typedef __attribute__((address_space(3))) void lds_void;
#define GLOAD_LDS16(g, l) \
    __builtin_amdgcn_global_load_lds((g_void*)(g), (lds_void*)(l), 16, 0, 0)

constexpr int Bsz   = 128;
constexpr int Lq    = 32;
constexpr int Ld    = 512;
constexpr int H     = 768;
constexpr int D     = 128;
constexpr int QROWS = Bsz * Lq;          // 4096
constexpr int DROWS = Bsz * Ld;          // 65536
constexpr int MTOT  = QROWS + 2 * DROWS; // 135168
constexpr int BM    = 128;               // rows per block
constexpr int BK    = 32;                // K per tile (16 KB f32)
constexpr int NKT   = H / BK;            // 24 K-tiles
static_assert(QROWS % BM == 0 && DROWS % BM == 0, "block never spans sources");
static_assert(NKT == 24, "loop peel below assumes 24 K-tiles");

// f32 -> bf16 bits, round-to-nearest-even
static __device__ __forceinline__ unsigned short f2b(float f) {
    unsigned int u = __builtin_bit_cast(unsigned int, f);
    unsigned int r = u + 0x7FFFu + ((u >> 16) & 1u);
    return (unsigned short)(r >> 16);
}

// ---------------------------------------------------------------------------
// Kernel 1: Wt[d][h] = bf16(W[h][d])
// ---------------------------------------------------------------------------
__global__ void prep_w_kernel(const float* __restrict__ W,
                              unsigned short* __restrict__ Wt) {
    int idx = blockIdx.x * 256 + threadIdx.x;
    if (idx < H * D) {
        int d = idx / H, h = idx % H;
        Wt[idx] = f2b(W[h * D + d]);
    }
}

// ---------------------------------------------------------------------------
// Kernel 2: projection, DEPTH-3 pipelined staging (issue-to-use = 3 iters for
//   both the A-stage (global_load_lds ring, 4 bufs) and the Wt register
//   prefetch (4 static slots, statically indexed via 4-step unroll).
//   Per iter: s_waitcnt vmcnt(8) -> s_barrier -> issue W(kt+3),S(kt+3)
//   -> compute(kt).  8 KB/wave stays in flight across every wait.
// ---------------------------------------------------------------------------
__global__ __launch_bounds__(512, 4) void proj_norm_kernel(
    const float* __restrict__ qh, const float* __restrict__ pdh,
    const float* __restrict__ ndh, const float* __restrict__ bias,
    const int* __restrict__ pdm, const int* __restrict__ ndm,
    const unsigned short* __restrict__ Wt, unsigned short* __restrict__ emb)
{
    __shared__ float Abuf[4][BM * BK];   // 4 x 16 KB ring
    __shared__ float ssred[4][BM];       // cross-wave norm partials (2 KB)

    const int tid  = threadIdx.x;
    const int lane = tid & 63, wave = tid >> 6;      // wave 0..7
    const int l15  = lane & 15, lg = lane >> 4;
    const int mg   = wave >> 2;                      // 0..1 (row half)
    const int ng   = wave & 3;                       // 0..3 (col quarter)
    const long row0 = (long)blockIdx.x * BM;

    const float* src; const int* mask; long srow;
    if (row0 < QROWS)              { src = qh;  srow = row0;                 mask = nullptr; }
    else if (row0 < QROWS + DROWS) { src = pdh; srow = row0 - QROWS;         mask = pdm; }
    else                           { src = ndh; srow = row0 - QROWS - DROWS; mask = ndm; }

    // staging: wave stages instrs {2w, 2w+1} (rows 16w..16w+15); lane l ->
    // row (l&7), 16B chunk (l>>3)^(l&7)  (XOR pre-swizzle, rule 21)
    const int rA = lane & 7;
    const int cA = (lane >> 3) ^ (lane & 7);
    const float* gs0 = src + (srow + 16 * wave     + rA) * (long)H + cA * 4;
    const float* gs1 = src + (srow + 16 * wave + 8 + rA) * (long)H + cA * 4;

    auto stage = [&](int bi, int kt) {
        GLOAD_LDS16(gs0 + kt * BK, &Abuf[bi][(2 * wave)     * 256]);
        GLOAD_LDS16(gs1 + kt * BK, &Abuf[bi][(2 * wave + 1) * 256]);
    };

    const unsigned short* wp = Wt + (size_t)(ng * 32 + l15) * H + lg * 8;
    auto loadwb = [&](int kt, v8s& w0, v8s& w1) {
        w0 = *(const v8s*)(wp + (size_t)kt * BK);
        w1 = *(const v8s*)(wp + (size_t)16 * H + (size_t)kt * BK);
    };

    const float bv0 = bias[ng * 32 + l15];
    const float bv1 = bias[ng * 32 + 16 + l15];

    v4f acc[4][2];
#pragma unroll
    for (int mt = 0; mt < 4; ++mt)
#pragma unroll
        for (int nt = 0; nt < 2; ++nt) acc[mt][nt] = (v4f){0.f, 0.f, 0.f, 0.f};

    auto compute = [&](const float* bufk, v8s wb0, v8s wb1) {
#pragma unroll
        for (int mt = 0; mt < 4; ++mt) {
            const int r  = mg * 64 + mt * 16 + l15;
            const int r7 = r & 7;
            const int a0 = (r >> 3) * 256 + ((((2 * lg)     ^ r7) * 8) + r7) * 4;
            const int a1 = (r >> 3) * 256 + ((((2 * lg + 1) ^ r7) * 8) + r7) * 4;
            float4 f0 = *(const float4*)(bufk + a0);
            float4 f1 = *(const float4*)(bufk + a1);
            v8s a;
            a[0] = (short)f2b(f0.x); a[1] = (short)f2b(f0.y);
            a[2] = (short)f2b(f0.z); a[3] = (short)f2b(f0.w);
            a[4] = (short)f2b(f1.x); a[5] = (short)f2b(f1.y);
            a[6] = (short)f2b(f1.z); a[7] = (short)f2b(f1.w);
            acc[mt][0] = MFMA16(a, wb0, acc[mt][0]);
            acc[mt][1] = MFMA16(a, wb1, acc[mt][1]);
        }
    };

    v8s w00, w01, w10, w11, w20, w21, w30, w31;

    // prologue: pairs for kt = 0,1,2  (FIFO: [W0,S0,W1,S1,W2,S2] x2 = 12)
    loadwb(0, w00, w01); stage(0, 0);
    loadwb(1, w10, w11); stage(1, 1);
    loadwb(2, w20, w21); stage(2, 2);

    // per-iter: wait vmcnt(8) completes pair kt, leaves pairs kt+1..kt+3
#define PROJ_STEP(BI, WB0, WB1, PW0, PW1, PBI, KT, VM)                    \
    {                                                                      \
        asm volatile("s_waitcnt vmcnt(" #VM ")" ::: "memory");             \
        __builtin_amdgcn_sched_barrier(0);                                 \
        __builtin_amdgcn_s_barrier();                                      \
        if ((KT) + 3 < NKT) {                                              \
            loadwb((KT) + 3, PW0, PW1);                                    \
            stage(PBI, (KT) + 3);                                          \
        }                                                                  \
        compute(&Abuf[BI][0], WB0, WB1);                                   \
    }

#pragma unroll 1
    for (int kt = 0; kt < NKT - 4; kt += 4) {
        PROJ_STEP(0, w00, w01, w30, w31, 3, kt,     8);
        PROJ_STEP(1, w10, w11, w00, w01, 0, kt + 1, 8);
        PROJ_STEP(2, w20, w21, w10, w11, 1, kt + 2, 8);
        PROJ_STEP(3, w30, w31, w20, w21, 2, kt + 3, 8);
    }
    PROJ_STEP(0, w00, w01, w30, w31, 3, NKT - 4, 8);   // kt=20, issues pair 23
    PROJ_STEP(1, w10, w11, w00, w01, 0, NKT - 3, 8);   // kt=21
    PROJ_STEP(2, w20, w21, w10, w11, 1, NKT - 2, 4);   // kt=22
    PROJ_STEP(3, w30, w31, w20, w21, 2, NKT - 1, 0);   // kt=23
#undef PROJ_STEP

    // ---- epilogue: bias, cross-wave L2-norm, mask, store bf16 ----
    float ss[4][4];
#pragma unroll
    for (int mt = 0; mt < 4; ++mt)
#pragma unroll
        for (int q = 0; q < 4; ++q) {
            float v0 = acc[mt][0][q] + bv0;
            float v1 = acc[mt][1][q] + bv1;
            acc[mt][0][q] = v0; acc[mt][1][q] = v1;
            ss[mt][q] = v0 * v0 + v1 * v1;
        }
#pragma unroll
    for (int off = 1; off < 16; off <<= 1)
#pragma unroll
        for (int mt = 0; mt < 4; ++mt)
#pragma unroll
            for (int q = 0; q < 4; ++q)
                ss[mt][q] += __shfl_xor(ss[mt][q], off);

    if (l15 == 0) {
#pragma unroll
        for (int mt = 0; mt < 4; ++mt)
#pragma unroll
            for (int q = 0; q < 4; ++q)
                ssred[ng][mg * 64 + mt * 16 + lg * 4 + q] = ss[mt][q];
    }
    __syncthreads();

#pragma unroll
    for (int mt = 0; mt < 4; ++mt)
#pragma unroll
        for (int q = 0; q < 4; ++q) {
            const int row = mg * 64 + mt * 16 + lg * 4 + q;
            float t = ssred[0][row] + ssred[1][row] + ssred[2][row] + ssred[3][row];
            float s = 1.0f / fmaxf(sqrtf(t), 1e-12f);
            if (mask) s *= (float)mask[srow + row];
            unsigned short* op = emb + (size_t)(row0 + row) * D + ng * 32 + l15;
            op[0]  = f2b(acc[mt][0][q] * s);
            op[16] = f2b(acc[mt][1][q] * s);
        }
}

// ---------------------------------------------------------------------------
// Kernel 3: MaxSim. One block per (batch, side); 4 waves x 128 doc tokens.
// ---------------------------------------------------------------------------
__global__ __launch_bounds__(256) void maxsim_kernel(
    const unsigned short* __restrict__ emb, float* __restrict__ out)
{
    const int blk  = blockIdx.x;       // 0..255
    const int b    = blk >> 1, side = blk & 1;
    const int wave = threadIdx.x >> 6, lane = threadIdx.x & 63;
    const int l15  = lane & 15, lg = lane >> 4;

    const unsigned short* Q  = emb + (size_t)(b * Lq) * D;
    const unsigned short* Dm = emb + (size_t)(QROWS + side * DROWS + b * Ld) * D;

    v4f acc[2][8];
#pragma unroll
    for (int m = 0; m < 2; ++m)
#pragma unroll
        for (int n = 0; n < 8; ++n) acc[m][n] = (v4f){0.f, 0.f, 0.f, 0.f};

    const int tok0 = wave * 128;
#pragma unroll
    for (int kk = 0; kk < 4; ++kk) {
        const int k0 = kk * 32 + lg * 8;
        v8s qa0 = *(const v8s*)(Q + (size_t)(l15) * D + k0);
        v8s qa1 = *(const v8s*)(Q + (size_t)(16 + l15) * D + k0);
#pragma unroll
        for (int n = 0; n < 8; ++n) {
            v8s db = *(const v8s*)(Dm + (size_t)(tok0 + n * 16 + l15) * D + k0);
            acc[0][n] = MFMA16(qa0, db, acc[0][n]);
            acc[1][n] = MFMA16(qa1, db, acc[1][n]);
        }
    }

    float mx[2][4];
#pragma unroll
    for (int m = 0; m < 2; ++m)
#pragma unroll
        for (int r = 0; r < 4; ++r) {
            float v = acc[m][0][r];
#pragma unroll
            for (int n = 1; n < 8; ++n) v = fmaxf(v, acc[m][n][r]);
            mx[m][r] = v;
        }
#pragma unroll
    for (int off = 1; off < 16; off <<= 1) {
#pragma unroll
        for (int m = 0; m < 2; ++m)
#pragma unroll
            for (int r = 0; r < 4; ++r)
                mx[m][r] = fmaxf(mx[m][r], __shfl_xor(mx[m][r], off));
    }

    __shared__ float red[4][32];
    if (l15 == 0) {
#pragma unroll
        for (int m = 0; m < 2; ++m)
#pragma unroll
            for (int r = 0; r < 4; ++r)
                red[wave][m * 16 + lg * 4 + r] = mx[m][r];
    }
    __syncthreads();

    if (threadIdx.x < 32) {
        int q = threadIdx.x;
        float v = fmaxf(fmaxf(red[0][q], red[1][q]), fmaxf(red[2][q], red[3][q]));
#pragma unroll
        for (int off = 1; off < 32; off <<= 1) v += __shfl_xor(v, off);
        if (q == 0) out[blk] = v;
    }
}

// ---------------------------------------------------------------------------
extern "C" void kernel_launch(void* const* d_in, const int* in_sizes, int n_in,
                              void* d_out, int out_size, void* d_ws, size_t ws_size,
                              hipStream_t stream)
{
    const float* qh   = (const float*)d_in[0];
    const float* pdh  = (const float*)d_in[1];
    const float* ndh  = (const float*)d_in[2];
    const float* W    = (const float*)d_in[3];
    const float* bias = (const float*)d_in[4];
    const int*   pdm  = (const int*)d_in[5];
    const int*   ndm  = (const int*)d_in[6];
    float* out = (float*)d_out;

    unsigned short* Wt  = (unsigned short*)d_ws;          // [D][H] bf16, 192 KB
    unsigned short* emb = Wt + (size_t)H * D;             // [MTOT][D] bf16

    prep_w_kernel<<<(H * D + 255) / 256, 256, 0, stream>>>(W, Wt);
    proj_norm_kernel<<<MTOT / BM, 512, 0, stream>>>(qh, pdh, ndh, bias, pdm, ndm, Wt, emb);
    maxsim_kernel<<<Bsz * 2, 256, 0, stream>>>(emb, out);
}